// Round 1
// baseline (321.292 us; speedup 1.0000x reference)
//
#include <hip/hip_runtime.h>
#include <math.h>

// NeuroGameTransformer: fused per-batch-row kernel, fp32 correctness baseline.
// Grid = B(256) blocks (1 per CU), 256 threads.
// Phases per block b:
//  0: transpose coalitions into LDS cT[n][k]
//  1: cs[k][d] = sum_n c[k,n]*h[b,n,d]          (thread owns d = t, t+256, t+512)
//  2: proj[k][e] = sum_d cs[k][d]*Wv[d][e]; v[k]=relu(||proj_k||*scale)
//  3: shapley from v
//  4: m0 = tanh((pooled@Wp+bp)*0.1); 25 damped mean-field iters (J in LDS, reusing cs region)
//  5: free energy; MLP (LN+GELU x2) -> logits

constexpr int Bq = 256, Sq = 128, Dq = 768, Nq = 128, Kq = 25, NCq = 3;
constexpr float GAMMA_ = 0.25f;
constexpr int T_MF_ = 25;
constexpr float DAMP_ = 0.7f;

constexpr int SH_CS   = 0;                 // 19200 floats (cs 25x768; later J 128x128=16384)
constexpr int SH_CT   = 19200;             // 3584  (cT 128x28, padded)
constexpr int SH_VSH  = 22784;             // 32
constexpr int SH_M    = 22816;             // 128
constexpr int SH_X1   = 22944;             // 256
constexpr int SH_X2   = 23200;             // 128
constexpr int SH_RED  = 23328;             // 128
constexpr int SH_TOT  = 23456;             // floats -> 93824 bytes

__device__ __forceinline__ float block_sum(float v, float* red) {
  const int t = threadIdx.x;
  const int lane = t & 63, wid = t >> 6;
  #pragma unroll
  for (int o = 32; o > 0; o >>= 1) v += __shfl_down(v, o, 64);
  __syncthreads();                 // protect red from previous use
  if (lane == 0) red[wid] = v;
  __syncthreads();
  return red[0] + red[1] + red[2] + red[3];
}

__global__ __launch_bounds__(256, 1) void ngt_fused(
    const float* __restrict__ hst,  const float* __restrict__ coal,
    const float* __restrict__ Wv,   const float* __restrict__ scale,
    const float* __restrict__ lf,   const float* __restrict__ Jg,
    const float* __restrict__ Wp,   const float* __restrict__ bp,
    const float* __restrict__ W1,   const float* __restrict__ b1,
    const float* __restrict__ g1,   const float* __restrict__ be1,
    const float* __restrict__ W2,   const float* __restrict__ b2,
    const float* __restrict__ g2,   const float* __restrict__ be2,
    const float* __restrict__ W3,   const float* __restrict__ b3,
    float* __restrict__ out)
{
  extern __shared__ float smem[];
  float* cs   = smem + SH_CS;
  float* cT   = smem + SH_CT;
  float* vsh  = smem + SH_VSH;
  float* m_sh = smem + SH_M;
  float* x_sh = smem + SH_X1;
  float* x2sh = smem + SH_X2;
  float* red  = smem + SH_RED;

  const int t = threadIdx.x;
  const int b = blockIdx.x;
  const int lane = t & 63, wid = t >> 6;
  const float* hb = hst + (size_t)b * (Sq * Dq);

  // ---- Phase 0: coalition transpose (cT[n][k]) ----
  for (int idx = t; idx < Kq * Nq; idx += 256) {
    const int k = idx >> 7, n = idx & 127;
    cT[n * 28 + k] = coal[idx];
  }
  __syncthreads();

  // ---- Phase 1: cs = coalitions @ feats ----
  float acc[Kq][3];
  #pragma unroll
  for (int k = 0; k < Kq; ++k) { acc[k][0] = 0.f; acc[k][1] = 0.f; acc[k][2] = 0.f; }
  for (int n = 0; n < Nq; ++n) {
    const float h0 = hb[n * Dq + t];
    const float h1 = hb[n * Dq + t + 256];
    const float h2 = hb[n * Dq + t + 512];
    float4 cq[7];
    const float4* csrc = reinterpret_cast<const float4*>(cT + n * 28);
    #pragma unroll
    for (int q = 0; q < 7; ++q) cq[q] = csrc[q];
    const float* carr = reinterpret_cast<const float*>(cq);
    #pragma unroll
    for (int k = 0; k < Kq; ++k) {
      const float cv = carr[k];
      acc[k][0] += cv * h0; acc[k][1] += cv * h1; acc[k][2] += cv * h2;
    }
  }
  #pragma unroll
  for (int k = 0; k < Kq; ++k) {
    cs[k * Dq + t]       = acc[k][0];
    cs[k * Dq + t + 256] = acc[k][1];
    cs[k * Dq + t + 512] = acc[k][2];
  }
  __syncthreads();

  // ---- Phase 2: proj = cs @ Wv, row norms -> v ----
  float pr[Kq][3];
  #pragma unroll
  for (int k = 0; k < Kq; ++k) { pr[k][0] = 0.f; pr[k][1] = 0.f; pr[k][2] = 0.f; }
  #pragma unroll 2
  for (int dt = 0; dt < Dq; dt += 4) {
    float w[4][3];
    #pragma unroll
    for (int i = 0; i < 4; ++i)
      #pragma unroll
      for (int j = 0; j < 3; ++j)
        w[i][j] = Wv[(dt + i) * Dq + t + j * 256];
    #pragma unroll
    for (int k = 0; k < Kq; ++k) {
      const float4 c4 = *reinterpret_cast<const float4*>(cs + k * Dq + dt);  // wave-uniform broadcast
      #pragma unroll
      for (int j = 0; j < 3; ++j)
        pr[k][j] += c4.x * w[0][j] + c4.y * w[1][j] + c4.z * w[2][j] + c4.w * w[3][j];
    }
  }
  const float sc0 = scale[0];
  #pragma unroll
  for (int k = 0; k < Kq; ++k) {
    float s = pr[k][0] * pr[k][0] + pr[k][1] * pr[k][1] + pr[k][2] * pr[k][2];
    #pragma unroll
    for (int o = 32; o > 0; o >>= 1) s += __shfl_down(s, o, 64);
    if (lane == 0) red[wid * Kq + k] = s;
  }
  __syncthreads();
  if (t < Kq) {
    const float nv = red[t] + red[Kq + t] + red[2 * Kq + t] + red[3 * Kq + t];
    vsh[t] = fmaxf(sqrtf(nv) * sc0, 0.0f);   // relu(norm*scale)
  }
  __syncthreads();

  // ---- Phase 3 (waves 0-1): shapley + m0 ; (waves 2-3): stage J into LDS ----
  float mloc = 0.f, lfv = 0.f;
  if (t < Nq) {
    float sw = 0.f, c1 = 0.f, vs = 0.f;
    #pragma unroll
    for (int k = 0; k < Kq; ++k) {
      const float c = cT[t * 28 + k];
      const float vk = vsh[k];
      sw += c * vk; vs += vk; c1 += c;
    }
    const float c0 = (float)Kq - c1;
    float shap = 0.f;
    if (c1 > 0.5f && c0 > 0.5f)
      shap = sw / fmaxf(c1, 1.f) - (vs - sw) / fmaxf(c0, 1.f);
    out[Bq * NCq + Bq + (size_t)b * Nq + t] = shap;

    // m0 = tanh((pooled @ Wp + bp) * 0.1)
    float a = bp[t];
    for (int d = 0; d < Dq; d += 4) {
      const float4 p4 = *reinterpret_cast<const float4*>(hb + d);  // uniform -> scalar loads
      a += p4.x * Wp[(d + 0) * Nq + t] + p4.y * Wp[(d + 1) * Nq + t]
         + p4.z * Wp[(d + 2) * Nq + t] + p4.w * Wp[(d + 3) * Nq + t];
    }
    mloc = tanhf(a * 0.1f);
    m_sh[t] = mloc;
    lfv = lf[t];
  } else {
    // stage J (fp32, 64 KB) into the retired cs region
    float4* Jl4 = reinterpret_cast<float4*>(cs);
    const float4* Jg4 = reinterpret_cast<const float4*>(Jg);
    for (int i = t - 128; i < (Nq * Nq) / 4; i += 128) Jl4[i] = Jg4[i];
  }
  __syncthreads();

  // ---- Phase 4: mean-field iterations ----
  const float* Jl = cs;
  const float Jdiag = (t < Nq) ? Jl[t * Nq + t] : 0.f;
  for (int it = 0; it <= T_MF_; ++it) {
    float hs = 0.f;
    if (t < Nq) {
      hs = lfv - mloc * Jdiag;   // exclude diagonal (Jm has zero diag)
      #pragma unroll 8
      for (int n2 = 0; n2 < Nq; n2 += 4) {
        const float4 m4 = *reinterpret_cast<const float4*>(m_sh + n2);
        hs += m4.x * Jl[(n2 + 0) * Nq + t];
        hs += m4.y * Jl[(n2 + 1) * Nq + t];
        hs += m4.z * Jl[(n2 + 2) * Nq + t];
        hs += m4.w * Jl[(n2 + 3) * Nq + t];
      }
    }
    if (it < T_MF_) {
      if (t < Nq) {
        const float nw = tanhf(hs * (1.0f / GAMMA_));
        mloc = DAMP_ * nw + (1.0f - DAMP_) * mloc;
      }
      __syncthreads();
      if (t < Nq) m_sh[t] = mloc;
      __syncthreads();
    } else {
      // free energy from h_fin: logaddexp(a,-a) = |a| + log1p(exp(-2|a|))
      const float a2 = fabsf(hs * (1.0f / GAMMA_));
      const float fe = (t < Nq) ? (a2 + log1pf(expf(-2.0f * a2))) : 0.f;
      const float tot = block_sum(fe, red);
      if (t == 0) out[Bq * NCq + b] = -GAMMA_ * tot;
    }
  }

  // ---- Phase 5: MLP head ----
  // layer 1: 256 outputs
  float u = b1[t];
  #pragma unroll 4
  for (int n = 0; n < Nq; n += 4) {
    const float4 m4 = *reinterpret_cast<const float4*>(m_sh + n);
    u += m4.x * W1[(n + 0) * 256 + t] + m4.y * W1[(n + 1) * 256 + t]
       + m4.z * W1[(n + 2) * 256 + t] + m4.w * W1[(n + 3) * 256 + t];
  }
  const float mean1 = block_sum(u, red) * (1.0f / 256.0f);
  const float xm1 = u - mean1;
  const float var1 = block_sum(xm1 * xm1, red) * (1.0f / 256.0f);
  const float xln1 = xm1 * rsqrtf(var1 + 1e-5f) * g1[t] + be1[t];
  x_sh[t] = 0.5f * xln1 * (1.0f + erff(xln1 * 0.70710678118654752f));
  __syncthreads();

  // layer 2: 128 outputs
  float u2 = 0.f;
  if (t < Nq) {
    u2 = b2[t];
    #pragma unroll 4
    for (int n = 0; n < 256; n += 4) {
      const float4 x4 = *reinterpret_cast<const float4*>(x_sh + n);
      u2 += x4.x * W2[(n + 0) * Nq + t] + x4.y * W2[(n + 1) * Nq + t]
          + x4.z * W2[(n + 2) * Nq + t] + x4.w * W2[(n + 3) * Nq + t];
    }
  }
  const float mean2 = block_sum(t < Nq ? u2 : 0.f, red) * (1.0f / 128.0f);
  const float xm2 = u2 - mean2;
  const float var2 = block_sum(t < Nq ? xm2 * xm2 : 0.f, red) * (1.0f / 128.0f);
  if (t < Nq) {
    const float xln2 = xm2 * rsqrtf(var2 + 1e-5f) * g2[t] + be2[t];
    x2sh[t] = 0.5f * xln2 * (1.0f + erff(xln2 * 0.70710678118654752f));
  }
  __syncthreads();

  // logits: 3 outputs
  if (t < NCq) {
    float lg = b3[t];
    #pragma unroll 4
    for (int n = 0; n < Nq; ++n) lg += x2sh[n] * W3[n * NCq + t];
    out[(size_t)b * NCq + t] = lg;
  }
}

extern "C" void kernel_launch(void* const* d_in, const int* in_sizes, int n_in,
                              void* d_out, int out_size, void* d_ws, size_t ws_size,
                              hipStream_t stream) {
  const float* hst   = (const float*)d_in[0];
  const float* coal  = (const float*)d_in[1];
  const float* Wv    = (const float*)d_in[2];
  const float* scale = (const float*)d_in[3];
  const float* lf    = (const float*)d_in[4];
  const float* Jg    = (const float*)d_in[5];
  const float* Wp    = (const float*)d_in[6];
  const float* bp    = (const float*)d_in[7];
  const float* W1    = (const float*)d_in[8];
  const float* b1    = (const float*)d_in[9];
  const float* g1    = (const float*)d_in[10];
  const float* be1   = (const float*)d_in[11];
  const float* W2    = (const float*)d_in[12];
  const float* b2    = (const float*)d_in[13];
  const float* g2    = (const float*)d_in[14];
  const float* be2   = (const float*)d_in[15];
  const float* W3    = (const float*)d_in[16];
  const float* b3    = (const float*)d_in[17];
  float* out = (float*)d_out;

  const size_t shmem = (size_t)SH_TOT * sizeof(float);  // 93,824 B (< 160 KiB/CU)
  // Defensive: allow >64 KiB dynamic LDS (ignore result if unsupported).
  (void)hipFuncSetAttribute(reinterpret_cast<const void*>(ngt_fused),
                            hipFuncAttributeMaxDynamicSharedMemorySize, (int)shmem);

  hipLaunchKernelGGL(ngt_fused, dim3(Bq), dim3(256), shmem, stream,
                     hst, coal, Wv, scale, lf, Jg, Wp, bp,
                     W1, b1, g1, be1, W2, b2, g2, be2, W3, b3, out);
}

// Round 3
// 122.867 us; speedup vs baseline: 2.6149x; 2.6149x over previous
//
#include <hip/hip_runtime.h>
#include <math.h>

// NeuroGameTransformer — 4-kernel MFMA pipeline.
// K0: WvT fp16 transpose.  K1: cs (fp32 regs -> fp16 ws) + m0.
// K2: fp16 MFMA GEMM (6400x768 @ 768x768) -> row sum-of-squares (vsq partials).
//     (round-3 fix: cross-wave LDS reduction in epilogue — was a write race)
// K3: shapley + mean-field + free-energy + MLP head.

typedef _Float16 h8 __attribute__((ext_vector_type(8)));
typedef float f4v __attribute__((ext_vector_type(4)));

constexpr int Bq = 256, Dq = 768, Nq = 128, Kq = 25;
// ws layout (bytes)
constexpr size_t WVT_OFF  = 0;                    // 768*768*2   = 1,179,648
constexpr size_t CS_OFF   = 1179648;              // 6400*768*2  = 9,830,400
constexpr size_t PART_OFF = 11010048;             // 4*6400*4    =   102,400
constexpr size_t M0_OFF   = 11112448;             // 256*128*4   =   131,072

// ---------------- K0: Wv (768x768 f32) -> WvT (768x768 fp16), transposed ----
__global__ __launch_bounds__(256, 1) void k0_wvt(const float* __restrict__ Wv,
                                                 _Float16* __restrict__ wvt) {
  __shared__ float tile[32 * 33];
  const int t = threadIdx.x;
  const int bx = blockIdx.x % 24, by = blockIdx.x / 24;  // bx: e-tile, by: d-tile
  const int r = t >> 3, c4 = (t & 7) * 4;
  const float4 v = *reinterpret_cast<const float4*>(Wv + (size_t)(by * 32 + r) * 768 + bx * 32 + c4);
  tile[r * 33 + c4 + 0] = v.x; tile[r * 33 + c4 + 1] = v.y;
  tile[r * 33 + c4 + 2] = v.z; tile[r * 33 + c4 + 3] = v.w;
  __syncthreads();
  _Float16* dp = wvt + (size_t)(bx * 32 + r) * 768 + by * 32 + c4;
  dp[0] = (_Float16)tile[(c4 + 0) * 33 + r];
  dp[1] = (_Float16)tile[(c4 + 1) * 33 + r];
  dp[2] = (_Float16)tile[(c4 + 2) * 33 + r];
  dp[3] = (_Float16)tile[(c4 + 3) * 33 + r];
}

// ---------------- K1: per-b front: cs fp16 + m0 -------------------------------
__global__ __launch_bounds__(256, 1) void k1_front(const float* __restrict__ hst,
                                                   const float* __restrict__ coal,
                                                   const float* __restrict__ Wp,
                                                   const float* __restrict__ bp,
                                                   _Float16* __restrict__ csf,
                                                   float* __restrict__ m0g) {
  __shared__ float cT[128 * 28];
  __shared__ float part2[256];
  const int t = threadIdx.x, b = blockIdx.x;
  const float* hb = hst + (size_t)b * (128 * 768);

  // coalition transpose into LDS (cT[n][k])
  for (int idx = t; idx < Kq * Nq; idx += 256)
    cT[(idx & 127) * 28 + (idx >> 7)] = coal[idx];
  __syncthreads();

  // cs[k][d] accumulate: thread owns cols t, t+256, t+512
  float acc[Kq][3];
  #pragma unroll
  for (int k = 0; k < Kq; ++k) { acc[k][0] = 0.f; acc[k][1] = 0.f; acc[k][2] = 0.f; }
  for (int n = 0; n < 128; n += 8) {
    float hv[8][3];
    #pragma unroll
    for (int i = 0; i < 8; ++i) {
      hv[i][0] = hb[(n + i) * 768 + t];
      hv[i][1] = hb[(n + i) * 768 + t + 256];
      hv[i][2] = hb[(n + i) * 768 + t + 512];
    }
    #pragma unroll
    for (int i = 0; i < 8; ++i) {
      const float4* cp = reinterpret_cast<const float4*>(cT + (n + i) * 28);
      float4 cq[7];
      #pragma unroll
      for (int q = 0; q < 7; ++q) cq[q] = cp[q];
      const float* ca = reinterpret_cast<const float*>(cq);
      #pragma unroll
      for (int k = 0; k < Kq; ++k) {
        acc[k][0] += ca[k] * hv[i][0];
        acc[k][1] += ca[k] * hv[i][1];
        acc[k][2] += ca[k] * hv[i][2];
      }
    }
  }
  const size_t rb = (size_t)b * 25;
  #pragma unroll
  for (int k = 0; k < Kq; ++k) {
    csf[(rb + k) * 768 + t]       = (_Float16)acc[k][0];
    csf[(rb + k) * 768 + t + 256] = (_Float16)acc[k][1];
    csf[(rb + k) * 768 + t + 512] = (_Float16)acc[k][2];
  }

  // m0 = tanh((pooled @ Wp + bp)*0.1): 2-way d-split over 256 threads
  const int j = t & 127, sg = t >> 7;
  float s = 0.f;
  for (int d = sg * 384; d < sg * 384 + 384; d += 4) {
    const float4 p4 = *reinterpret_cast<const float4*>(hb + d);
    s += p4.x * Wp[(d + 0) * 128 + j] + p4.y * Wp[(d + 1) * 128 + j]
       + p4.z * Wp[(d + 2) * 128 + j] + p4.w * Wp[(d + 3) * 128 + j];
  }
  part2[t] = s;
  __syncthreads();
  if (t < 128) {
    const float a0 = bp[t] + part2[t] + part2[t + 128];
    m0g[b * 128 + t] = tanhf(a0 * 0.1f);
  }
}

// ---------------- K2: fp16 MFMA norm-GEMM -------------------------------------
// rows 6400 (=256*25), cols 768, K=768. Grid 200 = 50 rowgroups x 4 colchunks(192).
// 8 waves: wave = (wm in 2) x (wn in 4); wave tile = 4 Mtiles x 3 Ntiles (16x16).
__global__ __launch_bounds__(512, 1) void k2_norm(const _Float16* __restrict__ csA,
                                                  const _Float16* __restrict__ wvtB,
                                                  float* __restrict__ part) {
  __shared__ __align__(16) char lds[(128 + 192) * 64];  // A 8192 B | B 12288 B
  char* ldsA = lds;
  char* ldsB = lds + 8192;
  const int tid = threadIdx.x, l = tid & 63, w = tid >> 6;
  const int rg = blockIdx.x >> 2, cc = blockIdx.x & 3;
  const size_t rowbase = (size_t)rg * 128;
  const int colbase = cc * 192;
  const int wm = w & 1, wn = w >> 1;

  // fragment LDS byte offsets (XOR swizzle: chunk ^= (row>>1)&3)
  const int fch = ((l >> 4) ^ (((l & 15) >> 1) & 3)) * 16;
  const int aoff = (l & 15) * 64 + fch;   // + (wm*4+mt)*1024
  const int boff = (l & 15) * 64 + fch;   // + (wn*3+nt)*1024

  // staging addresses
  const int srow = tid >> 2, sich = tid & 3;
  const int sch = sich ^ ((srow >> 1) & 3);
  const size_t gA_base = (rowbase + srow) * 768 + sich * 8;
  const size_t gB0_base = (size_t)(colbase + srow) * 768 + sich * 8;
  const size_t gB1_base = (size_t)(colbase + 128 + srow) * 768 + sich * 8;
  char* ldsA_w = ldsA + srow * 64 + sch * 16;
  char* ldsB0_w = ldsB + srow * 64 + sch * 16;
  char* ldsB1_w = ldsB + (128 + srow) * 64 + sch * 16;

  f4v acc[4][3];
  #pragma unroll
  for (int mt = 0; mt < 4; ++mt)
    #pragma unroll
    for (int nt = 0; nt < 3; ++nt) acc[mt][nt] = (f4v){0.f, 0.f, 0.f, 0.f};

  uint4 ra = *reinterpret_cast<const uint4*>(csA + gA_base);
  uint4 rb0 = *reinterpret_cast<const uint4*>(wvtB + gB0_base);
  uint4 rb1 = {0, 0, 0, 0};
  if (tid < 256) rb1 = *reinterpret_cast<const uint4*>(wvtB + gB1_base);

  for (int ks = 0; ks < 24; ++ks) {
    *reinterpret_cast<uint4*>(ldsA_w) = ra;
    *reinterpret_cast<uint4*>(ldsB0_w) = rb0;
    if (tid < 256) *reinterpret_cast<uint4*>(ldsB1_w) = rb1;
    if (ks < 23) {  // prefetch next K-panel into regs (hides latency under MFMA)
      ra = *reinterpret_cast<const uint4*>(csA + gA_base + (ks + 1) * 32);
      rb0 = *reinterpret_cast<const uint4*>(wvtB + gB0_base + (ks + 1) * 32);
      if (tid < 256) rb1 = *reinterpret_cast<const uint4*>(wvtB + gB1_base + (ks + 1) * 32);
    }
    __syncthreads();
    h8 af[4];
    #pragma unroll
    for (int mt = 0; mt < 4; ++mt)
      af[mt] = *reinterpret_cast<const h8*>(ldsA + (wm * 4 + mt) * 1024 + aoff);
    #pragma unroll
    for (int nt = 0; nt < 3; ++nt) {
      const h8 bf = *reinterpret_cast<const h8*>(ldsB + (wn * 3 + nt) * 1024 + boff);
      #pragma unroll
      for (int mt = 0; mt < 4; ++mt)
        acc[mt][nt] = __builtin_amdgcn_mfma_f32_16x16x32_f16(af[mt], bf, acc[mt][nt], 0, 0, 0);
    }
    __syncthreads();
  }

  // epilogue: per-row sum of squares over this col-chunk.
  // Step 1: in-wave reduce over 16 cols (lanes l&15) -> per-row partial per wave.
  // Step 2: cross-wave reduce over the 4 wn-waves via LDS (fixes round-2 race).
  float* redw = reinterpret_cast<float*>(lds);   // 128 rows x 4 wn = 2 KB
  #pragma unroll
  for (int mt = 0; mt < 4; ++mt) {
    #pragma unroll
    for (int r = 0; r < 4; ++r) {
      float s = acc[mt][0][r] * acc[mt][0][r] + acc[mt][1][r] * acc[mt][1][r]
              + acc[mt][2][r] * acc[mt][2][r];
      s += __shfl_xor(s, 1); s += __shfl_xor(s, 2);
      s += __shfl_xor(s, 4); s += __shfl_xor(s, 8);
      if ((l & 15) == 0) {
        const int row_local = (wm * 4 + mt) * 16 + (l >> 4) * 4 + r;
        redw[row_local * 4 + wn] = s;
      }
    }
  }
  __syncthreads();
  if (tid < 128) {
    const float tot = redw[tid * 4 + 0] + redw[tid * 4 + 1]
                    + redw[tid * 4 + 2] + redw[tid * 4 + 3];
    part[(size_t)cc * 6400 + rowbase + tid] = tot;
  }
}

// ---------------- K3: shapley + mean-field + FE + MLP -------------------------
__device__ __forceinline__ float bsum4(float v, float* red) {
  #pragma unroll
  for (int o = 32; o > 0; o >>= 1) v += __shfl_down(v, o, 64);
  __syncthreads();
  if ((threadIdx.x & 63) == 0) red[threadIdx.x >> 6] = v;
  __syncthreads();
  return red[0] + red[1] + red[2] + red[3];
}

__global__ __launch_bounds__(256, 1) void k3_back(
    const float* __restrict__ Jg,   const float* __restrict__ lf,
    const float* __restrict__ m0g,  const float* __restrict__ part,
    const float* __restrict__ coal, const float* __restrict__ scale,
    const float* __restrict__ W1, const float* __restrict__ b1,
    const float* __restrict__ g1, const float* __restrict__ be1,
    const float* __restrict__ W2, const float* __restrict__ b2,
    const float* __restrict__ g2, const float* __restrict__ be2,
    const float* __restrict__ W3, const float* __restrict__ b3,
    float* __restrict__ out) {
  extern __shared__ float sm[];
  float* Jl   = sm;             // 16384
  float* m_sh = sm + 16384;     // 128
  float* pmf  = sm + 16512;     // 256
  float* vsh  = sm + 16768;     // 32
  float* x1   = sm + 16800;     // 256
  float* x2   = sm + 17056;     // 128
  float* red  = sm + 17184;     // 8
  const int t = threadIdx.x, b = blockIdx.x;

  // stage J (64 KB) into LDS
  float4* J4 = reinterpret_cast<float4*>(Jl);
  const float4* Jg4 = reinterpret_cast<const float4*>(Jg);
  for (int i = t; i < 4096; i += 256) J4[i] = Jg4[i];
  // v[k] = relu(sqrt(sum of 4 col-chunk partials) * scale)
  if (t < 25) {
    const float sq = part[b * 25 + t] + part[6400 + b * 25 + t]
                   + part[12800 + b * 25 + t] + part[19200 + b * 25 + t];
    vsh[t] = fmaxf(sqrtf(sq) * scale[0], 0.f);
  }
  __syncthreads();

  // shapley
  if (t < 128) {
    float sw = 0.f, c1 = 0.f, vs = 0.f;
    #pragma unroll
    for (int k = 0; k < 25; ++k) {
      const float c = coal[k * 128 + t];
      const float vk = vsh[k];
      sw += c * vk; vs += vk; c1 += c;
    }
    const float c0 = 25.f - c1;
    float shap = 0.f;
    if (c1 > 0.5f && c0 > 0.5f)
      shap = sw / fmaxf(c1, 1.f) - (vs - sw) / fmaxf(c0, 1.f);
    out[1024 + b * 128 + t] = shap;
  }

  // mean-field init
  const int tn = t & 127, th = t >> 7;
  float mloc = 0.f, lfv = 0.f, Jdg = 0.f;
  if (t < 128) {
    mloc = m0g[b * 128 + t];
    m_sh[t] = mloc;
    lfv = lf[t];
    Jdg = Jl[t * 128 + t];
  }
  __syncthreads();

  // 25 damped iterations + final field pass (split-sum over 2 halves)
  float hs = 0.f;
  for (int it = 0; it <= 25; ++it) {
    float ps = 0.f;
    const int nb = th * 64;
    #pragma unroll 4
    for (int n2 = nb; n2 < nb + 64; n2 += 4) {
      const float4 m4 = *reinterpret_cast<const float4*>(m_sh + n2);
      ps += m4.x * Jl[(n2 + 0) * 128 + tn] + m4.y * Jl[(n2 + 1) * 128 + tn]
          + m4.z * Jl[(n2 + 2) * 128 + tn] + m4.w * Jl[(n2 + 3) * 128 + tn];
    }
    pmf[t] = ps;
    __syncthreads();
    if (it < 25) {
      if (t < 128) {
        const float h = lfv - mloc * Jdg + pmf[t] + pmf[t + 128];
        mloc = 0.7f * tanhf(h * 4.0f) + 0.3f * mloc;
        m_sh[t] = mloc;
      }
      __syncthreads();
    } else {
      if (t < 128) hs = lfv - mloc * Jdg + pmf[t] + pmf[t + 128];
    }
  }

  // free energy: logaddexp(a,-a) = |a| + log1p(exp(-2|a|))
  {
    const float a2 = (t < 128) ? fabsf(hs * 4.0f) : 0.f;
    const float fe = (t < 128) ? (a2 + log1pf(expf(-2.f * a2))) : 0.f;
    const float tot = bsum4(fe, red);
    if (t == 0) out[768 + b] = -0.25f * tot;
  }

  // MLP head
  float u = b1[t];
  #pragma unroll 4
  for (int n = 0; n < 128; n += 4) {
    const float4 m4 = *reinterpret_cast<const float4*>(m_sh + n);
    u += m4.x * W1[(n + 0) * 256 + t] + m4.y * W1[(n + 1) * 256 + t]
       + m4.z * W1[(n + 2) * 256 + t] + m4.w * W1[(n + 3) * 256 + t];
  }
  const float mean1 = bsum4(u, red) * (1.f / 256.f);
  const float xm1 = u - mean1;
  const float var1 = bsum4(xm1 * xm1, red) * (1.f / 256.f);
  const float xln1 = xm1 * rsqrtf(var1 + 1e-5f) * g1[t] + be1[t];
  x1[t] = 0.5f * xln1 * (1.f + erff(xln1 * 0.70710678118654752f));
  __syncthreads();

  float u2 = 0.f;
  if (t < 128) {
    u2 = b2[t];
    #pragma unroll 4
    for (int n = 0; n < 256; n += 4) {
      const float4 x4 = *reinterpret_cast<const float4*>(x1 + n);
      u2 += x4.x * W2[(n + 0) * 128 + t] + x4.y * W2[(n + 1) * 128 + t]
          + x4.z * W2[(n + 2) * 128 + t] + x4.w * W2[(n + 3) * 128 + t];
    }
  }
  const float mean2 = bsum4(t < 128 ? u2 : 0.f, red) * (1.f / 128.f);
  const float xm2 = u2 - mean2;
  const float var2 = bsum4(t < 128 ? xm2 * xm2 : 0.f, red) * (1.f / 128.f);
  if (t < 128) {
    const float xln2 = xm2 * rsqrtf(var2 + 1e-5f) * g2[t] + be2[t];
    x2[t] = 0.5f * xln2 * (1.f + erff(xln2 * 0.70710678118654752f));
  }
  __syncthreads();

  if (t < 3) {
    float lg = b3[t];
    #pragma unroll 4
    for (int n = 0; n < 128; ++n) lg += x2[n] * W3[n * 3 + t];
    out[b * 3 + t] = lg;
  }
}

// ---------------- launch ------------------------------------------------------
extern "C" void kernel_launch(void* const* d_in, const int* in_sizes, int n_in,
                              void* d_out, int out_size, void* d_ws, size_t ws_size,
                              hipStream_t stream) {
  const float* hst   = (const float*)d_in[0];
  const float* coal  = (const float*)d_in[1];
  const float* Wv    = (const float*)d_in[2];
  const float* scale = (const float*)d_in[3];
  const float* lf    = (const float*)d_in[4];
  const float* Jg    = (const float*)d_in[5];
  const float* Wp    = (const float*)d_in[6];
  const float* bp    = (const float*)d_in[7];
  const float* W1    = (const float*)d_in[8];
  const float* b1    = (const float*)d_in[9];
  const float* g1    = (const float*)d_in[10];
  const float* be1   = (const float*)d_in[11];
  const float* W2    = (const float*)d_in[12];
  const float* b2    = (const float*)d_in[13];
  const float* g2    = (const float*)d_in[14];
  const float* be2   = (const float*)d_in[15];
  const float* W3    = (const float*)d_in[16];
  const float* b3    = (const float*)d_in[17];
  float* out = (float*)d_out;

  char* ws = (char*)d_ws;  // needs >= 11,243,520 bytes
  _Float16* wvt = (_Float16*)(ws + WVT_OFF);
  _Float16* csf = (_Float16*)(ws + CS_OFF);
  float* part   = (float*)(ws + PART_OFF);
  float* m0g    = (float*)(ws + M0_OFF);

  const size_t k3_lds = 17192 * sizeof(float);  // 68,768 B
  (void)hipFuncSetAttribute(reinterpret_cast<const void*>(k3_back),
                            hipFuncAttributeMaxDynamicSharedMemorySize, (int)k3_lds);

  hipLaunchKernelGGL(k0_wvt, dim3(576), dim3(256), 0, stream, Wv, wvt);
  hipLaunchKernelGGL(k1_front, dim3(256), dim3(256), 0, stream, hst, coal, Wp, bp, csf, m0g);
  hipLaunchKernelGGL(k2_norm, dim3(200), dim3(512), 0, stream, csf, wvt, part);
  hipLaunchKernelGGL(k3_back, dim3(256), dim3(256), k3_lds, stream,
                     Jg, lf, m0g, part, coal, scale,
                     W1, b1, g1, be1, W2, b2, g2, be2, W3, b3, out);
}

// Round 4
// 102.410 us; speedup vs baseline: 3.1373x; 1.1998x over previous
//
#include <hip/hip_runtime.h>
#include <math.h>

// NeuroGameTransformer — 4-kernel MFMA pipeline.
// K0: WvT fp16 transpose.  K1: cs (fp32 regs -> fp16 ws) + m0.
//     (round-4: K1 split 3x along d -> 768 blocks, 3 blocks/CU, occupancy fix)
// K2: fp16 MFMA GEMM (6400x768 @ 768x768) -> row sum-of-squares (vsq partials).
// K3: shapley + mean-field + free-energy + MLP head.

typedef _Float16 h8 __attribute__((ext_vector_type(8)));
typedef float f4v __attribute__((ext_vector_type(4)));

constexpr int Bq = 256, Dq = 768, Nq = 128, Kq = 25;
// ws layout (bytes)
constexpr size_t WVT_OFF  = 0;                    // 768*768*2   = 1,179,648
constexpr size_t CS_OFF   = 1179648;              // 6400*768*2  = 9,830,400
constexpr size_t PART_OFF = 11010048;             // 4*6400*4    =   102,400
constexpr size_t M0_OFF   = 11112448;             // 256*128*4   =   131,072

// ---------------- K0: Wv (768x768 f32) -> WvT (768x768 fp16), transposed ----
__global__ __launch_bounds__(256, 1) void k0_wvt(const float* __restrict__ Wv,
                                                 _Float16* __restrict__ wvt) {
  __shared__ float tile[32 * 33];
  const int t = threadIdx.x;
  const int bx = blockIdx.x % 24, by = blockIdx.x / 24;  // bx: e-tile, by: d-tile
  const int r = t >> 3, c4 = (t & 7) * 4;
  const float4 v = *reinterpret_cast<const float4*>(Wv + (size_t)(by * 32 + r) * 768 + bx * 32 + c4);
  tile[r * 33 + c4 + 0] = v.x; tile[r * 33 + c4 + 1] = v.y;
  tile[r * 33 + c4 + 2] = v.z; tile[r * 33 + c4 + 3] = v.w;
  __syncthreads();
  _Float16* dp = wvt + (size_t)(bx * 32 + r) * 768 + by * 32 + c4;
  dp[0] = (_Float16)tile[(c4 + 0) * 33 + r];
  dp[1] = (_Float16)tile[(c4 + 1) * 33 + r];
  dp[2] = (_Float16)tile[(c4 + 2) * 33 + r];
  dp[3] = (_Float16)tile[(c4 + 3) * 33 + r];
}

// ---------------- K1: per-(b, d-chunk) front: cs fp16 + m0 --------------------
// grid = 768: b = blockIdx & 255, dq = blockIdx >> 8 (3 chunks of 256 cols).
// Each thread owns ONE d-column; acc[25] in regs. dq==0 blocks also compute m0.
__global__ __launch_bounds__(256, 2) void k1_front(const float* __restrict__ hst,
                                                   const float* __restrict__ coal,
                                                   const float* __restrict__ Wp,
                                                   const float* __restrict__ bp,
                                                   _Float16* __restrict__ csf,
                                                   float* __restrict__ m0g) {
  __shared__ float cT[128 * 28];
  __shared__ float part2[256];
  const int t = threadIdx.x;
  const int b = blockIdx.x & 255;
  const int dq = blockIdx.x >> 8;
  const float* hb = hst + (size_t)b * (128 * 768);
  const int col = dq * 256 + t;

  // coalition transpose into LDS (cT[n][k])
  for (int idx = t; idx < Kq * Nq; idx += 256)
    cT[(idx & 127) * 28 + (idx >> 7)] = coal[idx];
  __syncthreads();

  float acc[Kq];
  #pragma unroll
  for (int k = 0; k < Kq; ++k) acc[k] = 0.f;

  for (int n = 0; n < 128; n += 8) {
    float hv[8];
    #pragma unroll
    for (int i = 0; i < 8; ++i) hv[i] = hb[(n + i) * 768 + col];
    #pragma unroll
    for (int i = 0; i < 8; ++i) {
      const float4* cp = reinterpret_cast<const float4*>(cT + (n + i) * 28);
      #pragma unroll
      for (int q = 0; q < 6; ++q) {
        const float4 c4 = cp[q];
        acc[q * 4 + 0] += c4.x * hv[i];
        acc[q * 4 + 1] += c4.y * hv[i];
        acc[q * 4 + 2] += c4.z * hv[i];
        acc[q * 4 + 3] += c4.w * hv[i];
      }
      acc[24] += cT[(n + i) * 28 + 24] * hv[i];
    }
  }
  const size_t rb = (size_t)b * 25;
  #pragma unroll
  for (int k = 0; k < Kq; ++k)
    csf[(rb + k) * 768 + col] = (_Float16)acc[k];

  // m0 = tanh((pooled @ Wp + bp)*0.1): only the dq==0 blocks
  if (dq == 0) {
    const int j = t & 127, sg = t >> 7;
    float s = 0.f;
    for (int d = sg * 384; d < sg * 384 + 384; d += 4) {
      const float4 p4 = *reinterpret_cast<const float4*>(hb + d);
      s += p4.x * Wp[(d + 0) * 128 + j] + p4.y * Wp[(d + 1) * 128 + j]
         + p4.z * Wp[(d + 2) * 128 + j] + p4.w * Wp[(d + 3) * 128 + j];
    }
    part2[t] = s;
    __syncthreads();
    if (t < 128) {
      const float a0 = bp[t] + part2[t] + part2[t + 128];
      m0g[b * 128 + t] = tanhf(a0 * 0.1f);
    }
  }
}

// ---------------- K2: fp16 MFMA norm-GEMM -------------------------------------
// rows 6400 (=256*25), cols 768, K=768. Grid 200 = 50 rowgroups x 4 colchunks(192).
// 8 waves: wave = (wm in 2) x (wn in 4); wave tile = 4 Mtiles x 3 Ntiles (16x16).
__global__ __launch_bounds__(512, 1) void k2_norm(const _Float16* __restrict__ csA,
                                                  const _Float16* __restrict__ wvtB,
                                                  float* __restrict__ part) {
  __shared__ __align__(16) char lds[(128 + 192) * 64];  // A 8192 B | B 12288 B
  char* ldsA = lds;
  char* ldsB = lds + 8192;
  const int tid = threadIdx.x, l = tid & 63, w = tid >> 6;
  const int rg = blockIdx.x >> 2, cc = blockIdx.x & 3;
  const size_t rowbase = (size_t)rg * 128;
  const int colbase = cc * 192;
  const int wm = w & 1, wn = w >> 1;

  // fragment LDS byte offsets (XOR swizzle: chunk ^= (row>>1)&3)
  const int fch = ((l >> 4) ^ (((l & 15) >> 1) & 3)) * 16;
  const int aoff = (l & 15) * 64 + fch;   // + (wm*4+mt)*1024
  const int boff = (l & 15) * 64 + fch;   // + (wn*3+nt)*1024

  // staging addresses
  const int srow = tid >> 2, sich = tid & 3;
  const int sch = sich ^ ((srow >> 1) & 3);
  const size_t gA_base = (rowbase + srow) * 768 + sich * 8;
  const size_t gB0_base = (size_t)(colbase + srow) * 768 + sich * 8;
  const size_t gB1_base = (size_t)(colbase + 128 + srow) * 768 + sich * 8;
  char* ldsA_w = ldsA + srow * 64 + sch * 16;
  char* ldsB0_w = ldsB + srow * 64 + sch * 16;
  char* ldsB1_w = ldsB + (128 + srow) * 64 + sch * 16;

  f4v acc[4][3];
  #pragma unroll
  for (int mt = 0; mt < 4; ++mt)
    #pragma unroll
    for (int nt = 0; nt < 3; ++nt) acc[mt][nt] = (f4v){0.f, 0.f, 0.f, 0.f};

  uint4 ra = *reinterpret_cast<const uint4*>(csA + gA_base);
  uint4 rb0 = *reinterpret_cast<const uint4*>(wvtB + gB0_base);
  uint4 rb1 = {0, 0, 0, 0};
  if (tid < 256) rb1 = *reinterpret_cast<const uint4*>(wvtB + gB1_base);

  for (int ks = 0; ks < 24; ++ks) {
    *reinterpret_cast<uint4*>(ldsA_w) = ra;
    *reinterpret_cast<uint4*>(ldsB0_w) = rb0;
    if (tid < 256) *reinterpret_cast<uint4*>(ldsB1_w) = rb1;
    if (ks < 23) {  // prefetch next K-panel into regs (hides latency under MFMA)
      ra = *reinterpret_cast<const uint4*>(csA + gA_base + (ks + 1) * 32);
      rb0 = *reinterpret_cast<const uint4*>(wvtB + gB0_base + (ks + 1) * 32);
      if (tid < 256) rb1 = *reinterpret_cast<const uint4*>(wvtB + gB1_base + (ks + 1) * 32);
    }
    __syncthreads();
    h8 af[4];
    #pragma unroll
    for (int mt = 0; mt < 4; ++mt)
      af[mt] = *reinterpret_cast<const h8*>(ldsA + (wm * 4 + mt) * 1024 + aoff);
    #pragma unroll
    for (int nt = 0; nt < 3; ++nt) {
      const h8 bf = *reinterpret_cast<const h8*>(ldsB + (wn * 3 + nt) * 1024 + boff);
      #pragma unroll
      for (int mt = 0; mt < 4; ++mt)
        acc[mt][nt] = __builtin_amdgcn_mfma_f32_16x16x32_f16(af[mt], bf, acc[mt][nt], 0, 0, 0);
    }
    __syncthreads();
  }

  // epilogue: per-row sum of squares over this col-chunk.
  // Step 1: in-wave reduce over 16 cols (lanes l&15) -> per-row partial per wave.
  // Step 2: cross-wave reduce over the 4 wn-waves via LDS.
  float* redw = reinterpret_cast<float*>(lds);   // 128 rows x 4 wn = 2 KB
  #pragma unroll
  for (int mt = 0; mt < 4; ++mt) {
    #pragma unroll
    for (int r = 0; r < 4; ++r) {
      float s = acc[mt][0][r] * acc[mt][0][r] + acc[mt][1][r] * acc[mt][1][r]
              + acc[mt][2][r] * acc[mt][2][r];
      s += __shfl_xor(s, 1); s += __shfl_xor(s, 2);
      s += __shfl_xor(s, 4); s += __shfl_xor(s, 8);
      if ((l & 15) == 0) {
        const int row_local = (wm * 4 + mt) * 16 + (l >> 4) * 4 + r;
        redw[row_local * 4 + wn] = s;
      }
    }
  }
  __syncthreads();
  if (tid < 128) {
    const float tot = redw[tid * 4 + 0] + redw[tid * 4 + 1]
                    + redw[tid * 4 + 2] + redw[tid * 4 + 3];
    part[(size_t)cc * 6400 + rowbase + tid] = tot;
  }
}

// ---------------- K3: shapley + mean-field + FE + MLP -------------------------
__device__ __forceinline__ float bsum4(float v, float* red) {
  #pragma unroll
  for (int o = 32; o > 0; o >>= 1) v += __shfl_down(v, o, 64);
  __syncthreads();
  if ((threadIdx.x & 63) == 0) red[threadIdx.x >> 6] = v;
  __syncthreads();
  return red[0] + red[1] + red[2] + red[3];
}

__global__ __launch_bounds__(256, 1) void k3_back(
    const float* __restrict__ Jg,   const float* __restrict__ lf,
    const float* __restrict__ m0g,  const float* __restrict__ part,
    const float* __restrict__ coal, const float* __restrict__ scale,
    const float* __restrict__ W1, const float* __restrict__ b1,
    const float* __restrict__ g1, const float* __restrict__ be1,
    const float* __restrict__ W2, const float* __restrict__ b2,
    const float* __restrict__ g2, const float* __restrict__ be2,
    const float* __restrict__ W3, const float* __restrict__ b3,
    float* __restrict__ out) {
  extern __shared__ float sm[];
  float* Jl   = sm;             // 16384
  float* m_sh = sm + 16384;     // 128
  float* pmf  = sm + 16512;     // 256
  float* vsh  = sm + 16768;     // 32
  float* x1   = sm + 16800;     // 256
  float* x2   = sm + 17056;     // 128
  float* red  = sm + 17184;     // 8
  const int t = threadIdx.x, b = blockIdx.x;

  // stage J (64 KB) into LDS
  float4* J4 = reinterpret_cast<float4*>(Jl);
  const float4* Jg4 = reinterpret_cast<const float4*>(Jg);
  for (int i = t; i < 4096; i += 256) J4[i] = Jg4[i];
  // v[k] = relu(sqrt(sum of 4 col-chunk partials) * scale)
  if (t < 25) {
    const float sq = part[b * 25 + t] + part[6400 + b * 25 + t]
                   + part[12800 + b * 25 + t] + part[19200 + b * 25 + t];
    vsh[t] = fmaxf(sqrtf(sq) * scale[0], 0.f);
  }
  __syncthreads();

  // shapley
  if (t < 128) {
    float sw = 0.f, c1 = 0.f, vs = 0.f;
    #pragma unroll
    for (int k = 0; k < 25; ++k) {
      const float c = coal[k * 128 + t];
      const float vk = vsh[k];
      sw += c * vk; vs += vk; c1 += c;
    }
    const float c0 = 25.f - c1;
    float shap = 0.f;
    if (c1 > 0.5f && c0 > 0.5f)
      shap = sw / fmaxf(c1, 1.f) - (vs - sw) / fmaxf(c0, 1.f);
    out[1024 + b * 128 + t] = shap;
  }

  // mean-field init
  const int tn = t & 127, th = t >> 7;
  float mloc = 0.f, lfv = 0.f, Jdg = 0.f;
  if (t < 128) {
    mloc = m0g[b * 128 + t];
    m_sh[t] = mloc;
    lfv = lf[t];
    Jdg = Jl[t * 128 + t];
  }
  __syncthreads();

  // 25 damped iterations + final field pass (split-sum over 2 halves)
  float hs = 0.f;
  for (int it = 0; it <= 25; ++it) {
    float ps = 0.f;
    const int nb = th * 64;
    #pragma unroll 4
    for (int n2 = nb; n2 < nb + 64; n2 += 4) {
      const float4 m4 = *reinterpret_cast<const float4*>(m_sh + n2);
      ps += m4.x * Jl[(n2 + 0) * 128 + tn] + m4.y * Jl[(n2 + 1) * 128 + tn]
          + m4.z * Jl[(n2 + 2) * 128 + tn] + m4.w * Jl[(n2 + 3) * 128 + tn];
    }
    pmf[t] = ps;
    __syncthreads();
    if (it < 25) {
      if (t < 128) {
        const float h = lfv - mloc * Jdg + pmf[t] + pmf[t + 128];
        mloc = 0.7f * tanhf(h * 4.0f) + 0.3f * mloc;
        m_sh[t] = mloc;
      }
      __syncthreads();
    } else {
      if (t < 128) hs = lfv - mloc * Jdg + pmf[t] + pmf[t + 128];
    }
  }

  // free energy: logaddexp(a,-a) = |a| + log1p(exp(-2|a|))
  {
    const float a2 = (t < 128) ? fabsf(hs * 4.0f) : 0.f;
    const float fe = (t < 128) ? (a2 + log1pf(expf(-2.f * a2))) : 0.f;
    const float tot = bsum4(fe, red);
    if (t == 0) out[768 + b] = -0.25f * tot;
  }

  // MLP head
  float u = b1[t];
  #pragma unroll 4
  for (int n = 0; n < 128; n += 4) {
    const float4 m4 = *reinterpret_cast<const float4*>(m_sh + n);
    u += m4.x * W1[(n + 0) * 256 + t] + m4.y * W1[(n + 1) * 256 + t]
       + m4.z * W1[(n + 2) * 256 + t] + m4.w * W1[(n + 3) * 256 + t];
  }
  const float mean1 = bsum4(u, red) * (1.f / 256.f);
  const float xm1 = u - mean1;
  const float var1 = bsum4(xm1 * xm1, red) * (1.f / 256.f);
  const float xln1 = xm1 * rsqrtf(var1 + 1e-5f) * g1[t] + be1[t];
  x1[t] = 0.5f * xln1 * (1.f + erff(xln1 * 0.70710678118654752f));
  __syncthreads();

  float u2 = 0.f;
  if (t < 128) {
    u2 = b2[t];
    #pragma unroll 4
    for (int n = 0; n < 256; n += 4) {
      const float4 x4 = *reinterpret_cast<const float4*>(x1 + n);
      u2 += x4.x * W2[(n + 0) * 128 + t] + x4.y * W2[(n + 1) * 128 + t]
          + x4.z * W2[(n + 2) * 128 + t] + x4.w * W2[(n + 3) * 128 + t];
    }
  }
  const float mean2 = bsum4(t < 128 ? u2 : 0.f, red) * (1.f / 128.f);
  const float xm2 = u2 - mean2;
  const float var2 = bsum4(t < 128 ? xm2 * xm2 : 0.f, red) * (1.f / 128.f);
  if (t < 128) {
    const float xln2 = xm2 * rsqrtf(var2 + 1e-5f) * g2[t] + be2[t];
    x2[t] = 0.5f * xln2 * (1.f + erff(xln2 * 0.70710678118654752f));
  }
  __syncthreads();

  if (t < 3) {
    float lg = b3[t];
    #pragma unroll 4
    for (int n = 0; n < 128; ++n) lg += x2[n] * W3[n * 3 + t];
    out[b * 3 + t] = lg;
  }
}

// ---------------- launch ------------------------------------------------------
extern "C" void kernel_launch(void* const* d_in, const int* in_sizes, int n_in,
                              void* d_out, int out_size, void* d_ws, size_t ws_size,
                              hipStream_t stream) {
  const float* hst   = (const float*)d_in[0];
  const float* coal  = (const float*)d_in[1];
  const float* Wv    = (const float*)d_in[2];
  const float* scale = (const float*)d_in[3];
  const float* lf    = (const float*)d_in[4];
  const float* Jg    = (const float*)d_in[5];
  const float* Wp    = (const float*)d_in[6];
  const float* bp    = (const float*)d_in[7];
  const float* W1    = (const float*)d_in[8];
  const float* b1    = (const float*)d_in[9];
  const float* g1    = (const float*)d_in[10];
  const float* be1   = (const float*)d_in[11];
  const float* W2    = (const float*)d_in[12];
  const float* b2    = (const float*)d_in[13];
  const float* g2    = (const float*)d_in[14];
  const float* be2   = (const float*)d_in[15];
  const float* W3    = (const float*)d_in[16];
  const float* b3    = (const float*)d_in[17];
  float* out = (float*)d_out;

  char* ws = (char*)d_ws;  // needs >= 11,243,520 bytes
  _Float16* wvt = (_Float16*)(ws + WVT_OFF);
  _Float16* csf = (_Float16*)(ws + CS_OFF);
  float* part   = (float*)(ws + PART_OFF);
  float* m0g    = (float*)(ws + M0_OFF);

  const size_t k3_lds = 17192 * sizeof(float);  // 68,768 B
  (void)hipFuncSetAttribute(reinterpret_cast<const void*>(k3_back),
                            hipFuncAttributeMaxDynamicSharedMemorySize, (int)k3_lds);

  hipLaunchKernelGGL(k0_wvt, dim3(576), dim3(256), 0, stream, Wv, wvt);
  hipLaunchKernelGGL(k1_front, dim3(768), dim3(256), 0, stream, hst, coal, Wp, bp, csf, m0g);
  hipLaunchKernelGGL(k2_norm, dim3(200), dim3(512), 0, stream, csf, wvt, part);
  hipLaunchKernelGGL(k3_back, dim3(256), dim3(256), k3_lds, stream,
                     Jg, lf, m0g, part, coal, scale,
                     W1, b1, g1, be1, W2, b2, g2, be2, W3, b3, out);
}

// Round 5
// 89.178 us; speedup vs baseline: 3.6028x; 1.1484x over previous
//
#include <hip/hip_runtime.h>
#include <math.h>

// NeuroGameTransformer — 4-kernel MFMA pipeline.
// K0: WvT fp16 transpose.  K1: cs (fp32 regs -> fp16 ws) + m0 (3x d-split).
// K2: fp16 MFMA GEMM (6400x768 @ 768x768) -> row sum-of-squares (vsq partials).
// K3: shapley + mean-field + free-energy + MLP head.
//     (round-5: J held in 64 VGPRs/thread instead of 64 KB LDS — kills the
//      per-iteration LDS storm and the staging; LDS 68.8 KB -> ~3.5 KB)

typedef _Float16 h8 __attribute__((ext_vector_type(8)));
typedef float f4v __attribute__((ext_vector_type(4)));

constexpr int Bq = 256, Dq = 768, Nq = 128, Kq = 25;
// ws layout (bytes)
constexpr size_t WVT_OFF  = 0;                    // 768*768*2   = 1,179,648
constexpr size_t CS_OFF   = 1179648;              // 6400*768*2  = 9,830,400
constexpr size_t PART_OFF = 11010048;             // 4*6400*4    =   102,400
constexpr size_t M0_OFF   = 11112448;             // 256*128*4   =   131,072

// ---------------- K0: Wv (768x768 f32) -> WvT (768x768 fp16), transposed ----
__global__ __launch_bounds__(256, 1) void k0_wvt(const float* __restrict__ Wv,
                                                 _Float16* __restrict__ wvt) {
  __shared__ float tile[32 * 33];
  const int t = threadIdx.x;
  const int bx = blockIdx.x % 24, by = blockIdx.x / 24;  // bx: e-tile, by: d-tile
  const int r = t >> 3, c4 = (t & 7) * 4;
  const float4 v = *reinterpret_cast<const float4*>(Wv + (size_t)(by * 32 + r) * 768 + bx * 32 + c4);
  tile[r * 33 + c4 + 0] = v.x; tile[r * 33 + c4 + 1] = v.y;
  tile[r * 33 + c4 + 2] = v.z; tile[r * 33 + c4 + 3] = v.w;
  __syncthreads();
  _Float16* dp = wvt + (size_t)(bx * 32 + r) * 768 + by * 32 + c4;
  dp[0] = (_Float16)tile[(c4 + 0) * 33 + r];
  dp[1] = (_Float16)tile[(c4 + 1) * 33 + r];
  dp[2] = (_Float16)tile[(c4 + 2) * 33 + r];
  dp[3] = (_Float16)tile[(c4 + 3) * 33 + r];
}

// ---------------- K1: per-(b, d-chunk) front: cs fp16 + m0 --------------------
// grid = 768: b = blockIdx & 255, dq = blockIdx >> 8 (3 chunks of 256 cols).
__global__ __launch_bounds__(256, 2) void k1_front(const float* __restrict__ hst,
                                                   const float* __restrict__ coal,
                                                   const float* __restrict__ Wp,
                                                   const float* __restrict__ bp,
                                                   _Float16* __restrict__ csf,
                                                   float* __restrict__ m0g) {
  __shared__ float cT[128 * 28];
  __shared__ float part2[256];
  const int t = threadIdx.x;
  const int b = blockIdx.x & 255;
  const int dq = blockIdx.x >> 8;
  const float* hb = hst + (size_t)b * (128 * 768);
  const int col = dq * 256 + t;

  // coalition transpose into LDS (cT[n][k])
  for (int idx = t; idx < Kq * Nq; idx += 256)
    cT[(idx & 127) * 28 + (idx >> 7)] = coal[idx];
  __syncthreads();

  float acc[Kq];
  #pragma unroll
  for (int k = 0; k < Kq; ++k) acc[k] = 0.f;

  for (int n = 0; n < 128; n += 8) {
    float hv[8];
    #pragma unroll
    for (int i = 0; i < 8; ++i) hv[i] = hb[(n + i) * 768 + col];
    #pragma unroll
    for (int i = 0; i < 8; ++i) {
      const float4* cp = reinterpret_cast<const float4*>(cT + (n + i) * 28);
      #pragma unroll
      for (int q = 0; q < 6; ++q) {
        const float4 c4 = cp[q];
        acc[q * 4 + 0] += c4.x * hv[i];
        acc[q * 4 + 1] += c4.y * hv[i];
        acc[q * 4 + 2] += c4.z * hv[i];
        acc[q * 4 + 3] += c4.w * hv[i];
      }
      acc[24] += cT[(n + i) * 28 + 24] * hv[i];
    }
  }
  const size_t rb = (size_t)b * 25;
  #pragma unroll
  for (int k = 0; k < Kq; ++k)
    csf[(rb + k) * 768 + col] = (_Float16)acc[k];

  // m0 = tanh((pooled @ Wp + bp)*0.1): only the dq==0 blocks
  if (dq == 0) {
    const int j = t & 127, sg = t >> 7;
    float s = 0.f;
    for (int d = sg * 384; d < sg * 384 + 384; d += 4) {
      const float4 p4 = *reinterpret_cast<const float4*>(hb + d);
      s += p4.x * Wp[(d + 0) * 128 + j] + p4.y * Wp[(d + 1) * 128 + j]
         + p4.z * Wp[(d + 2) * 128 + j] + p4.w * Wp[(d + 3) * 128 + j];
    }
    part2[t] = s;
    __syncthreads();
    if (t < 128) {
      const float a0 = bp[t] + part2[t] + part2[t + 128];
      m0g[b * 128 + t] = tanhf(a0 * 0.1f);
    }
  }
}

// ---------------- K2: fp16 MFMA norm-GEMM -------------------------------------
__global__ __launch_bounds__(512, 1) void k2_norm(const _Float16* __restrict__ csA,
                                                  const _Float16* __restrict__ wvtB,
                                                  float* __restrict__ part) {
  __shared__ __align__(16) char lds[(128 + 192) * 64];  // A 8192 B | B 12288 B
  char* ldsA = lds;
  char* ldsB = lds + 8192;
  const int tid = threadIdx.x, l = tid & 63, w = tid >> 6;
  const int rg = blockIdx.x >> 2, cc = blockIdx.x & 3;
  const size_t rowbase = (size_t)rg * 128;
  const int colbase = cc * 192;
  const int wm = w & 1, wn = w >> 1;

  const int fch = ((l >> 4) ^ (((l & 15) >> 1) & 3)) * 16;
  const int aoff = (l & 15) * 64 + fch;
  const int boff = (l & 15) * 64 + fch;

  const int srow = tid >> 2, sich = tid & 3;
  const int sch = sich ^ ((srow >> 1) & 3);
  const size_t gA_base = (rowbase + srow) * 768 + sich * 8;
  const size_t gB0_base = (size_t)(colbase + srow) * 768 + sich * 8;
  const size_t gB1_base = (size_t)(colbase + 128 + srow) * 768 + sich * 8;
  char* ldsA_w = ldsA + srow * 64 + sch * 16;
  char* ldsB0_w = ldsB + srow * 64 + sch * 16;
  char* ldsB1_w = ldsB + (128 + srow) * 64 + sch * 16;

  f4v acc[4][3];
  #pragma unroll
  for (int mt = 0; mt < 4; ++mt)
    #pragma unroll
    for (int nt = 0; nt < 3; ++nt) acc[mt][nt] = (f4v){0.f, 0.f, 0.f, 0.f};

  uint4 ra = *reinterpret_cast<const uint4*>(csA + gA_base);
  uint4 rb0 = *reinterpret_cast<const uint4*>(wvtB + gB0_base);
  uint4 rb1 = {0, 0, 0, 0};
  if (tid < 256) rb1 = *reinterpret_cast<const uint4*>(wvtB + gB1_base);

  for (int ks = 0; ks < 24; ++ks) {
    *reinterpret_cast<uint4*>(ldsA_w) = ra;
    *reinterpret_cast<uint4*>(ldsB0_w) = rb0;
    if (tid < 256) *reinterpret_cast<uint4*>(ldsB1_w) = rb1;
    if (ks < 23) {
      ra = *reinterpret_cast<const uint4*>(csA + gA_base + (ks + 1) * 32);
      rb0 = *reinterpret_cast<const uint4*>(wvtB + gB0_base + (ks + 1) * 32);
      if (tid < 256) rb1 = *reinterpret_cast<const uint4*>(wvtB + gB1_base + (ks + 1) * 32);
    }
    __syncthreads();
    h8 af[4];
    #pragma unroll
    for (int mt = 0; mt < 4; ++mt)
      af[mt] = *reinterpret_cast<const h8*>(ldsA + (wm * 4 + mt) * 1024 + aoff);
    #pragma unroll
    for (int nt = 0; nt < 3; ++nt) {
      const h8 bf = *reinterpret_cast<const h8*>(ldsB + (wn * 3 + nt) * 1024 + boff);
      #pragma unroll
      for (int mt = 0; mt < 4; ++mt)
        acc[mt][nt] = __builtin_amdgcn_mfma_f32_16x16x32_f16(af[mt], bf, acc[mt][nt], 0, 0, 0);
    }
    __syncthreads();
  }

  // epilogue: per-row sum of squares; cross-wave reduce over the 4 wn-waves.
  float* redw = reinterpret_cast<float*>(lds);   // 128 rows x 4 wn = 2 KB
  #pragma unroll
  for (int mt = 0; mt < 4; ++mt) {
    #pragma unroll
    for (int r = 0; r < 4; ++r) {
      float s = acc[mt][0][r] * acc[mt][0][r] + acc[mt][1][r] * acc[mt][1][r]
              + acc[mt][2][r] * acc[mt][2][r];
      s += __shfl_xor(s, 1); s += __shfl_xor(s, 2);
      s += __shfl_xor(s, 4); s += __shfl_xor(s, 8);
      if ((l & 15) == 0) {
        const int row_local = (wm * 4 + mt) * 16 + (l >> 4) * 4 + r;
        redw[row_local * 4 + wn] = s;
      }
    }
  }
  __syncthreads();
  if (tid < 128) {
    const float tot = redw[tid * 4 + 0] + redw[tid * 4 + 1]
                    + redw[tid * 4 + 2] + redw[tid * 4 + 3];
    part[(size_t)cc * 6400 + rowbase + tid] = tot;
  }
}

// ---------------- K3: shapley + mean-field + FE + MLP -------------------------
__device__ __forceinline__ float bsum4(float v, float* red) {
  #pragma unroll
  for (int o = 32; o > 0; o >>= 1) v += __shfl_down(v, o, 64);
  __syncthreads();
  if ((threadIdx.x & 63) == 0) red[threadIdx.x >> 6] = v;
  __syncthreads();
  return red[0] + red[1] + red[2] + red[3];
}

__global__ __launch_bounds__(256, 1) void k3_back(
    const float* __restrict__ Jg,   const float* __restrict__ lf,
    const float* __restrict__ m0g,  const float* __restrict__ part,
    const float* __restrict__ coal, const float* __restrict__ scale,
    const float* __restrict__ W1, const float* __restrict__ b1,
    const float* __restrict__ g1, const float* __restrict__ be1,
    const float* __restrict__ W2, const float* __restrict__ b2,
    const float* __restrict__ g2, const float* __restrict__ be2,
    const float* __restrict__ W3, const float* __restrict__ b3,
    float* __restrict__ out) {
  __shared__ __align__(16) float m_sh[128];
  __shared__ float pmf[256];
  __shared__ float vsh[32];
  __shared__ __align__(16) float x1[256];
  __shared__ float x2[128];
  __shared__ float red[8];
  const int t = threadIdx.x, b = blockIdx.x;
  const int tn = t & 127, th = t >> 7;

  // J column tn, rows th*64 .. th*64+63 -> 64 VGPRs (coalesced across tn).
  // Fully unrolled so indexing stays compile-time (registers, not scratch).
  float Jreg[64];
  #pragma unroll
  for (int i = 0; i < 64; ++i)
    Jreg[i] = Jg[(size_t)(th * 64 + i) * 128 + tn];

  // v[k] = relu(sqrt(sum of 4 col-chunk partials) * scale)
  if (t < 25) {
    const float sq = part[b * 25 + t] + part[6400 + b * 25 + t]
                   + part[12800 + b * 25 + t] + part[19200 + b * 25 + t];
    vsh[t] = fmaxf(sqrtf(sq) * scale[0], 0.f);
  }
  __syncthreads();

  // shapley
  if (t < 128) {
    float sw = 0.f, c1 = 0.f, vs = 0.f;
    #pragma unroll
    for (int k = 0; k < 25; ++k) {
      const float c = coal[k * 128 + t];
      const float vk = vsh[k];
      sw += c * vk; vs += vk; c1 += c;
    }
    const float c0 = 25.f - c1;
    float shap = 0.f;
    if (c1 > 0.5f && c0 > 0.5f)
      shap = sw / fmaxf(c1, 1.f) - (vs - sw) / fmaxf(c0, 1.f);
    out[1024 + b * 128 + t] = shap;
  }

  // mean-field init
  float mloc = 0.f, lfv = 0.f, Jdg = 0.f;
  if (t < 128) {
    mloc = m0g[b * 128 + t];
    m_sh[t] = mloc;
    lfv = lf[t];
    Jdg = Jg[t * 128 + t];
  }
  __syncthreads();

  // 25 damped iterations + final field pass; J from registers, m from LDS.
  float hs = 0.f;
  for (int it = 0; it <= 25; ++it) {
    float ps0 = 0.f, ps1 = 0.f, ps2 = 0.f, ps3 = 0.f;
    #pragma unroll
    for (int q = 0; q < 16; ++q) {
      const float4 m4 = *reinterpret_cast<const float4*>(m_sh + th * 64 + q * 4);
      ps0 += Jreg[q * 4 + 0] * m4.x;
      ps1 += Jreg[q * 4 + 1] * m4.y;
      ps2 += Jreg[q * 4 + 2] * m4.z;
      ps3 += Jreg[q * 4 + 3] * m4.w;
    }
    pmf[t] = (ps0 + ps1) + (ps2 + ps3);
    __syncthreads();
    if (it < 25) {
      if (t < 128) {
        const float h = lfv - mloc * Jdg + pmf[t] + pmf[t + 128];
        mloc = 0.7f * tanhf(h * 4.0f) + 0.3f * mloc;
        m_sh[t] = mloc;
      }
      __syncthreads();
    } else {
      if (t < 128) hs = lfv - mloc * Jdg + pmf[t] + pmf[t + 128];
    }
  }

  // free energy: logaddexp(a,-a) = |a| + log1p(exp(-2|a|))
  {
    const float a2 = (t < 128) ? fabsf(hs * 4.0f) : 0.f;
    const float fe = (t < 128) ? (a2 + log1pf(expf(-2.f * a2))) : 0.f;
    const float tot = bsum4(fe, red);
    if (t == 0) out[768 + b] = -0.25f * tot;
  }

  // MLP head
  float u = b1[t];
  #pragma unroll 4
  for (int n = 0; n < 128; n += 4) {
    const float4 m4 = *reinterpret_cast<const float4*>(m_sh + n);
    u += m4.x * W1[(n + 0) * 256 + t] + m4.y * W1[(n + 1) * 256 + t]
       + m4.z * W1[(n + 2) * 256 + t] + m4.w * W1[(n + 3) * 256 + t];
  }
  const float mean1 = bsum4(u, red) * (1.f / 256.f);
  const float xm1 = u - mean1;
  const float var1 = bsum4(xm1 * xm1, red) * (1.f / 256.f);
  const float xln1 = xm1 * rsqrtf(var1 + 1e-5f) * g1[t] + be1[t];
  x1[t] = 0.5f * xln1 * (1.f + erff(xln1 * 0.70710678118654752f));
  __syncthreads();

  float u2 = 0.f;
  if (t < 128) {
    u2 = b2[t];
    #pragma unroll 4
    for (int n = 0; n < 256; n += 4) {
      const float4 x4 = *reinterpret_cast<const float4*>(x1 + n);
      u2 += x4.x * W2[(n + 0) * 128 + t] + x4.y * W2[(n + 1) * 128 + t]
          + x4.z * W2[(n + 2) * 128 + t] + x4.w * W2[(n + 3) * 128 + t];
    }
  }
  const float mean2 = bsum4(t < 128 ? u2 : 0.f, red) * (1.f / 128.f);
  const float xm2 = u2 - mean2;
  const float var2 = bsum4(t < 128 ? xm2 * xm2 : 0.f, red) * (1.f / 128.f);
  if (t < 128) {
    const float xln2 = xm2 * rsqrtf(var2 + 1e-5f) * g2[t] + be2[t];
    x2[t] = 0.5f * xln2 * (1.f + erff(xln2 * 0.70710678118654752f));
  }
  __syncthreads();

  if (t < 3) {
    float lg = b3[t];
    #pragma unroll 4
    for (int n = 0; n < 128; ++n) lg += x2[n] * W3[n * 3 + t];
    out[b * 3 + t] = lg;
  }
}

// ---------------- launch ------------------------------------------------------
extern "C" void kernel_launch(void* const* d_in, const int* in_sizes, int n_in,
                              void* d_out, int out_size, void* d_ws, size_t ws_size,
                              hipStream_t stream) {
  const float* hst   = (const float*)d_in[0];
  const float* coal  = (const float*)d_in[1];
  const float* Wv    = (const float*)d_in[2];
  const float* scale = (const float*)d_in[3];
  const float* lf    = (const float*)d_in[4];
  const float* Jg    = (const float*)d_in[5];
  const float* Wp    = (const float*)d_in[6];
  const float* bp    = (const float*)d_in[7];
  const float* W1    = (const float*)d_in[8];
  const float* b1    = (const float*)d_in[9];
  const float* g1    = (const float*)d_in[10];
  const float* be1   = (const float*)d_in[11];
  const float* W2    = (const float*)d_in[12];
  const float* b2    = (const float*)d_in[13];
  const float* g2    = (const float*)d_in[14];
  const float* be2   = (const float*)d_in[15];
  const float* W3    = (const float*)d_in[16];
  const float* b3    = (const float*)d_in[17];
  float* out = (float*)d_out;

  char* ws = (char*)d_ws;  // needs >= 11,243,520 bytes
  _Float16* wvt = (_Float16*)(ws + WVT_OFF);
  _Float16* csf = (_Float16*)(ws + CS_OFF);
  float* part   = (float*)(ws + PART_OFF);
  float* m0g    = (float*)(ws + M0_OFF);

  hipLaunchKernelGGL(k0_wvt, dim3(576), dim3(256), 0, stream, Wv, wvt);
  hipLaunchKernelGGL(k1_front, dim3(768), dim3(256), 0, stream, hst, coal, Wp, bp, csf, m0g);
  hipLaunchKernelGGL(k2_norm, dim3(200), dim3(512), 0, stream, csf, wvt, part);
  hipLaunchKernelGGL(k3_back, dim3(256), dim3(256), 0, stream,
                     Jg, lf, m0g, part, coal, scale,
                     W1, b1, g1, be1, W2, b2, g2, be2, W3, b3, out);
}